// Round 1
// baseline (84.309 us; speedup 1.0000x reference)
//
#include <hip/hip_runtime.h>

#define NMOL 1024
#define MOLSIZE 128

// Output layout (all float32, reference return order, flat):
// [0] nmol, [1] molsize, [2..2+1024) nHeavy, [1026..2050) nHydro, [2050..3074) nocc,
// [3074 +0/1/2*n_real) Z, maskd, atom_molid,
// P=3074+3*n_real: mask, pair_molid, ni, nj, idxi, idxj (np each), xij (3*np), rij (np)
//
// R6 structure: single fused kernel. The only cross-block dependency is the
// per-molecule (cnt_real, pair_tot) pair -> packed into ONE 32-bit word
// (bit31=published | pair_tot<<8 | cnt_real). Payload==flag, so RELAXED
// agent-scope atomics suffice (no separate data to fence). Each block
// publishes after its ballot sweep, then spin-reads all 1024 words and
// reduces the prefix locally (same redundant-prefix trick as the old K2,
// but without the second launch, without the 4MB bal_g round-trip, and
// without re-loading species/coords or re-scanning ballots).
//
// Co-residency requirement for the spin: grid=1024 = 4 blocks/CU x 256 CUs,
// guaranteed by __launch_bounds__(256, 4) (VGPR capped at 128, LDS ~7.8KB).
// Flags are zeroed by a 4KB hipMemsetAsync node (ws is re-poisoned per iter).

// Exact-reference arithmetic: f32 sub, (x^2+y^2)+z^2 without fma, sqrt.
__device__ __forceinline__ float pair_dist(float ax, float ay, float az,
                                           float bx, float by, float bz,
                                           float& dx, float& dy, float& dz) {
    dx = __fsub_rn(bx, ax);
    dy = __fsub_rn(by, ay);
    dz = __fsub_rn(bz, az);
    float d2 = __fadd_rn(__fadd_rn(__fmul_rn(dx, dx), __fmul_rn(dy, dy)), __fmul_rn(dz, dz));
    return __fsqrt_rn(d2);
}

__global__ __launch_bounds__(256, 4) void k_fused(const int* __restrict__ species,
                                                  const float* __restrict__ coord,
                                                  const float* __restrict__ tore,
                                                  float* __restrict__ out,
                                                  unsigned int* __restrict__ pub) {
    __shared__ float cx[MOLSIZE], cy[MOLSIZE], cz[MOLSIZE], spf[MOLSIZE];
    __shared__ int iv[MOLSIZE];  // LOCAL nonblank rank (mol_base added at use)
    __shared__ unsigned long long bal_s[256];
    __shared__ int sIncl[256];
    __shared__ int sH[2], sY[2], sN[2];
    __shared__ float sT[2];
    __shared__ int wpair[4], wtot[4];
    __shared__ int redALT[4], redAALL[4], redPLT[4], redPALL[4];
    __shared__ int wc0s;

    int m = blockIdx.x, t = threadIdx.x;
    int lane = t & 63, w = t >> 6;

    // ---- phase A: load + mol stats (waves 0,1 only; wave-uniform branch) ----
    int s_at = 0;
    unsigned long long amb = 0ull;
    if (t < MOLSIZE) {
        int f = m * MOLSIZE + t;
        s_at = species[f];
        bool nb = (s_at > 0);
        float x = coord[3 * f + 0], y = coord[3 * f + 1], z = coord[3 * f + 2];
        float sent = 1.0e30f * (float)(t + 1);  // blanks -> dist = inf, never selected
        cx[t] = nb ? x : sent;
        cy[t] = nb ? y : sent;
        cz[t] = nb ? z : sent;
        spf[t] = (float)s_at;
        amb = __ballot(nb);
        if (t == 0) wc0s = __popcll(amb);
        int h = (s_at > 1) ? 1 : 0, yy = (s_at == 1) ? 1 : 0, nn = nb ? 1 : 0;
        float tv = tore[s_at];  // integer-valued: reduction order exact
        for (int d = 32; d > 0; d >>= 1) {
            h += __shfl_down(h, d);
            yy += __shfl_down(yy, d);
            nn += __shfl_down(nn, d);
            tv += __shfl_down(tv, d);
        }
        if (lane == 0) { sH[w] = h; sY[w] = yy; sN[w] = nn; sT[w] = tv; }
    }
    __syncthreads();  // B1: cx/cy/cz/spf, per-wave stats ready
    if (t == 0) {
        out[2 + m] = (float)(sH[0] + sH[1]);
        out[2 + NMOL + m] = (float)(sY[0] + sY[1]);
        out[2 + 2 * NMOL + m] = (float)((int)((sT[0] + sT[1]) * 0.5f));
        if (m == 0) { out[0] = (float)NMOL; out[1] = (float)MOLSIZE; }
    }

    // ---- phase B: pair ballot sweep (chunk c = 2*a + (b>=64), bit = b&63) ----
    float bxl = cx[lane], byl = cy[lane], bzl = cz[lane];
    float bxh = cx[64 + lane], byh = cy[64 + lane], bzh = cz[64 + lane];
    int wcount = 0;
    for (int j = 0; j < 32; ++j) {
        int a = w + 4 * j;
        float ax = cx[a], ay = cy[a], az = cz[a];  // broadcast reads
        unsigned long long mb0 = 0ull, mb1 = 0ull;
        if (a < 63) {  // lo half: b = lane, need b > a
            float dx, dy, dz;
            float dist = pair_dist(ax, ay, az, bxl, byl, bzl, dx, dy, dz);
            mb0 = __ballot((lane > a) && (dist < 5.0f));
        }
        if (a < 127) {  // hi half: b = 64+lane, need b > a (matters for a >= 64!)
            float dx, dy, dz;
            float dist = pair_dist(ax, ay, az, bxh, byh, bzh, dx, dy, dz);
            mb1 = __ballot(((64 + lane) > a) && (dist < 5.0f));
        }
        if (lane == 0) { bal_s[2 * a] = mb0; bal_s[2 * a + 1] = mb1; }
        wcount += __popcll(mb0) + __popcll(mb1);
    }
    if (lane == 0) wpair[w] = wcount;
    __syncthreads();  // B2: bal_s, wpair complete

    // ---- publish packed counts ASAP (pair_tot <= 8128 fits 13 bits) ----
    if (t == 0) {
        unsigned int nreal = (unsigned int)(sN[0] + sN[1]);
        unsigned int ptot = (unsigned int)(wpair[0] + wpair[1] + wpair[2] + wpair[3]);
        __hip_atomic_store(&pub[m], 0x80000000u | (ptot << 8) | nreal,
                           __ATOMIC_RELAXED, __HIP_MEMORY_SCOPE_AGENT);
    }

    // ---- local work overlapped with other blocks publishing ----
    unsigned long long bal = bal_s[t];
    int v = __popcll(bal);
    for (int d = 1; d < 64; d <<= 1) {
        int u = __shfl_up(v, d);
        if (lane >= d) v += u;
    }
    if (lane == 63) wtot[w] = v;
    if (t < MOLSIZE && s_at > 0)
        iv[t] = __popcll(amb & ((1ull << lane) - 1ull)) + ((w == 1) ? wc0s : 0);
    __syncthreads();  // B3: wtot, iv visible
    int add = 0;
    for (int ww = 0; ww < w; ++ww) add += wtot[ww];
    sIncl[t] = v + add;

    // ---- spin-read all 1024 published words; thread t covers 4t..4t+3 ----
    unsigned int pw[4];
#pragma unroll
    for (int k = 0; k < 4; ++k) {
        unsigned int val = __hip_atomic_load(&pub[4 * t + k], __ATOMIC_RELAXED,
                                             __HIP_MEMORY_SCOPE_AGENT);
        while (!(val & 0x80000000u)) {
            __builtin_amdgcn_s_sleep(1);
            val = __hip_atomic_load(&pub[4 * t + k], __ATOMIC_RELAXED,
                                    __HIP_MEMORY_SCOPE_AGENT);
        }
        pw[k] = val;
    }
    int aLT = 0, aALL = 0, pLT = 0, pALL = 0;
    int i0 = 4 * t;
#pragma unroll
    for (int k = 0; k < 4; ++k) {
        int real = (int)(pw[k] & 0xFFu);
        int pr = (int)((pw[k] >> 8) & 0x1FFFu);
        aALL += real;
        pALL += pr;
        if (i0 + k < m) { aLT += real; pLT += pr; }
    }
    for (int d = 32; d > 0; d >>= 1) {
        aLT += __shfl_down(aLT, d);
        aALL += __shfl_down(aALL, d);
        pLT += __shfl_down(pLT, d);
        pALL += __shfl_down(pALL, d);
    }
    if (lane == 0) { redALT[w] = aLT; redAALL[w] = aALL; redPLT[w] = pLT; redPALL[w] = pALL; }
    __syncthreads();  // B4: red*, sIncl, iv visible

    int mol_base = redALT[0] + redALT[1] + redALT[2] + redALT[3];
    int n_real   = redAALL[0] + redAALL[1] + redAALL[2] + redAALL[3];
    int qbase    = redPLT[0] + redPLT[1] + redPLT[2] + redPLT[3];
    int npairs   = redPALL[0] + redPALL[1] + redPALL[2] + redPALL[3];

    // ---- atom outputs ----
    if (t < MOLSIZE && s_at > 0) {
        int g = mol_base + iv[t];
        out[3074 + g] = spf[t];
        out[3074 + n_real + g] = (float)(t * (MOLSIZE + 1) + m * (MOLSIZE * MOLSIZE));
        out[3074 + 2 * n_real + g] = (float)m;
    }
    int np_mol = sIncl[255];

    int offP = 3074 + 3 * n_real;
    float* pm0 = out + offP;
    float* pm1 = pm0 + npairs;
    float* pm2 = pm1 + npairs;
    float* pm3 = pm2 + npairs;
    float* pm4 = pm3 + npairs;
    float* pm5 = pm4 + npairs;
    float* px  = pm5 + npairs;
    float* pr  = px + 3 * npairs;
    float fm = (float)m;

    for (int q = t; q < np_mol; q += 256) {
        // binary search: c = first chunk with inclusive-scan > q
        int c = 0;
        if (sIncl[c + 127] <= q) c += 128;
        if (sIncl[c + 63] <= q) c += 64;
        if (sIncl[c + 31] <= q) c += 32;
        if (sIncl[c + 15] <= q) c += 16;
        if (sIncl[c + 7] <= q) c += 8;
        if (sIncl[c + 3] <= q) c += 4;
        if (sIncl[c + 1] <= q) c += 2;
        if (sIncl[c] <= q) c += 1;
        int r = q - (c ? sIncl[c - 1] : 0);
        unsigned long long mb = bal_s[c];
        // branchless select of r-th set bit
        unsigned int cur = (unsigned int)mb;
        int idx = 0;
        int cc = __popc(cur);
        if (r >= cc) { r -= cc; idx = 32; cur = (unsigned int)(mb >> 32); }
        cc = __popc(cur & 0xFFFFu); if (r >= cc) { r -= cc; idx += 16; cur >>= 16; }
        cc = __popc(cur & 0xFFu);   if (r >= cc) { r -= cc; idx += 8;  cur >>= 8; }
        cc = __popc(cur & 0xFu);    if (r >= cc) { r -= cc; idx += 4;  cur >>= 4; }
        cc = __popc(cur & 0x3u);    if (r >= cc) { r -= cc; idx += 2;  cur >>= 2; }
        cc = cur & 1u;              if (r >= cc) { idx += 1; }
        int a = c >> 1;
        int b = ((c & 1) << 6) | idx;
        float dx, dy, dz;
        float dist = pair_dist(cx[a], cy[a], cz[a], cx[b], cy[b], cz[b], dx, dy, dz);
        int Q = qbase + q;
        pm0[Q] = (float)(m * (MOLSIZE * MOLSIZE) + a * MOLSIZE + b);
        pm1[Q] = fm;
        pm2[Q] = spf[a];
        pm3[Q] = spf[b];
        pm4[Q] = (float)(mol_base + iv[a]);
        pm5[Q] = (float)(mol_base + iv[b]);
        px[3 * Q + 0] = __fdiv_rn(dx, dist);
        px[3 * Q + 1] = __fdiv_rn(dy, dist);
        px[3 * Q + 2] = __fdiv_rn(dz, dist);
        pr[Q] = __fmul_rn(dist, 1.8897261258369282f);
    }
}

extern "C" void kernel_launch(void* const* d_in, const int* in_sizes, int n_in,
                              void* d_out, int out_size, void* d_ws, size_t ws_size,
                              hipStream_t stream) {
    const int* species = (const int*)d_in[0];
    const float* coords = (const float*)d_in[1];
    const float* tore = (const float*)d_in[2];
    float* out = (float*)d_out;
    unsigned int* pub = (unsigned int*)d_ws;

    // ws is re-poisoned each iteration -> publish flags MUST be zeroed first.
    // 4KB memset node is graph-capturable and ~1-2us.
    hipMemsetAsync(pub, 0, NMOL * sizeof(unsigned int), stream);
    k_fused<<<NMOL, 256, 0, stream>>>(species, coords, tore, out, pub);
}

// Round 2
// 79.390 us; speedup vs baseline: 1.0620x; 1.0620x over previous
//
#include <hip/hip_runtime.h>

#define NMOL 1024
#define MOLSIZE 128
#define MPB 4              // molecules per block (4 independent 256-thread subgroups)
#define NBLK (NMOL / MPB)  // 256 workgroups = 1 per CU

// Output layout (all float32, reference return order, flat):
// [0] nmol, [1] molsize, [2..2+1024) nHeavy, [1026..2050) nHydro, [2050..3074) nocc,
// [3074 +0/1/2*n_real) Z, maskd, atom_molid,
// P=3074+3*n_real: mask, pair_molid, ni, nj, idxi, idxj (np each), xij (3*np), rij (np)
//
// R7 structure (post-mortem of R6): fused kernel was work-lean but no faster ->
// cost is per-workgroup dispatch ramp (~10-12us per 1024-wg grid), which the
// spin serializes in front of all work. Fix: 256 blocks x 1024 threads
// (same 4 waves/SIMD occupancy), 4 molecules/block as independent 256-thread
// subgroups. Ramp ~4x shorter; spin is ONE poll address per thread
// (thread t <-> molecule t); count table staged once in LDS and reused by all
// 4 subgroups' redundant prefix reductions.
//
// Cross-block dependency is still the packed per-molecule word in pub[]:
// bit31=published | pair_tot[13b]<<8 | cnt_real[8b]. Payload==flag -> relaxed
// agent-scope atomics suffice. Co-residency: 256 blocks <= 256 CUs, always
// resident. Flags zeroed by 4KB hipMemsetAsync (ws re-poisoned per iter).

// Exact-reference arithmetic: f32 sub, (x^2+y^2)+z^2 without fma, sqrt.
__device__ __forceinline__ float pair_dist(float ax, float ay, float az,
                                           float bx, float by, float bz,
                                           float& dx, float& dy, float& dz) {
    dx = __fsub_rn(bx, ax);
    dy = __fsub_rn(by, ay);
    dz = __fsub_rn(bz, az);
    float d2 = __fadd_rn(__fadd_rn(__fmul_rn(dx, dx), __fmul_rn(dy, dy)), __fmul_rn(dz, dz));
    return __fsqrt_rn(d2);
}

__global__ __launch_bounds__(1024) void k_fused(const int* __restrict__ species,
                                                const float* __restrict__ coord,
                                                const float* __restrict__ tore,
                                                float* __restrict__ out,
                                                unsigned int* __restrict__ pub) {
    __shared__ float cx[MPB][MOLSIZE], cy[MPB][MOLSIZE], cz[MPB][MOLSIZE], spf[MPB][MOLSIZE];
    __shared__ int iv[MPB][MOLSIZE];  // LOCAL nonblank rank (mol_base added at use)
    __shared__ unsigned long long bal_s[MPB][256];
    __shared__ int sIncl[MPB][256];
    __shared__ int sH[MPB][2], sY[MPB][2], sN[MPB][2];
    __shared__ float sT[MPB][2];
    __shared__ int wpair[MPB][4], wtot[MPB][4];
    __shared__ int redALT[MPB][4], redAALL[MPB][4], redPLT[MPB][4], redPALL[MPB][4];
    __shared__ int wc0s[MPB];
    __shared__ int pubR[NMOL], pubP[NMOL];  // staged count table, shared by subgroups

    int t = threadIdx.x;
    int g = t >> 8;        // subgroup = molecule slot 0..3
    int u = t & 255;       // thread index within subgroup
    int m = blockIdx.x * MPB + g;
    int lane = t & 63;     // lane within wave
    int wl = (t >> 6) & 3; // wave index within subgroup (0..3)

    // ---- phase A: load + mol stats (u<128 => waves {4g, 4g+1}; wave-uniform) ----
    int s_at = 0;
    unsigned long long amb = 0ull;
    if (u < MOLSIZE) {
        int f = m * MOLSIZE + u;
        s_at = species[f];
        bool nb = (s_at > 0);
        float x = coord[3 * f + 0], y = coord[3 * f + 1], z = coord[3 * f + 2];
        float sent = 1.0e30f * (float)(u + 1);  // blanks -> dist = inf, never selected
        cx[g][u] = nb ? x : sent;
        cy[g][u] = nb ? y : sent;
        cz[g][u] = nb ? z : sent;
        spf[g][u] = (float)s_at;
        amb = __ballot(nb);
        if (u == 0) wc0s[g] = __popcll(amb);
        int h = (s_at > 1) ? 1 : 0, yy = (s_at == 1) ? 1 : 0, nn = nb ? 1 : 0;
        float tv = tore[s_at];  // integer-valued: reduction order exact
        for (int d = 32; d > 0; d >>= 1) {
            h += __shfl_down(h, d);
            yy += __shfl_down(yy, d);
            nn += __shfl_down(nn, d);
            tv += __shfl_down(tv, d);
        }
        if (lane == 0) { sH[g][wl] = h; sY[g][wl] = yy; sN[g][wl] = nn; sT[g][wl] = tv; }
    }
    __syncthreads();  // B1: cx/cy/cz/spf + per-wave stats ready
    if (u == 0) {
        out[2 + m] = (float)(sH[g][0] + sH[g][1]);
        out[2 + NMOL + m] = (float)(sY[g][0] + sY[g][1]);
        out[2 + 2 * NMOL + m] = (float)((int)((sT[g][0] + sT[g][1]) * 0.5f));
        if (m == 0) { out[0] = (float)NMOL; out[1] = (float)MOLSIZE; }
    }

    // ---- phase B: pair ballot sweep (chunk c = 2*a + (b>=64), bit = b&63) ----
    float bxl = cx[g][lane], byl = cy[g][lane], bzl = cz[g][lane];
    float bxh = cx[g][64 + lane], byh = cy[g][64 + lane], bzh = cz[g][64 + lane];
    int wcount = 0;
    for (int j = 0; j < 32; ++j) {
        int a = wl + 4 * j;
        float ax = cx[g][a], ay = cy[g][a], az = cz[g][a];  // broadcast reads
        unsigned long long mb0 = 0ull, mb1 = 0ull;
        if (a < 63) {  // lo half: b = lane, need b > a
            float dx, dy, dz;
            float dist = pair_dist(ax, ay, az, bxl, byl, bzl, dx, dy, dz);
            mb0 = __ballot((lane > a) && (dist < 5.0f));
        }
        if (a < 127) {  // hi half: b = 64+lane, need b > a (matters for a >= 64!)
            float dx, dy, dz;
            float dist = pair_dist(ax, ay, az, bxh, byh, bzh, dx, dy, dz);
            mb1 = __ballot(((64 + lane) > a) && (dist < 5.0f));
        }
        if (lane == 0) { bal_s[g][2 * a] = mb0; bal_s[g][2 * a + 1] = mb1; }
        wcount += __popcll(mb0) + __popcll(mb1);
    }
    if (lane == 0) wpair[g][wl] = wcount;
    __syncthreads();  // B2: bal_s + wpair complete

    // ---- publish packed counts ASAP (pair_tot <= 8128 fits 13 bits) ----
    if (u == 0) {
        unsigned int nreal = (unsigned int)(sN[g][0] + sN[g][1]);
        unsigned int ptot =
            (unsigned int)(wpair[g][0] + wpair[g][1] + wpair[g][2] + wpair[g][3]);
        __hip_atomic_store(&pub[m], 0x80000000u | (ptot << 8) | nreal,
                           __ATOMIC_RELAXED, __HIP_MEMORY_SCOPE_AGENT);
    }

    // ---- local work overlapped with other blocks publishing ----
    unsigned long long bal = bal_s[g][u];
    int v = __popcll(bal);
    for (int d = 1; d < 64; d <<= 1) {
        int uu = __shfl_up(v, d);
        if (lane >= d) v += uu;
    }
    if (lane == 63) wtot[g][wl] = v;
    if (u < MOLSIZE && s_at > 0)
        iv[g][u] = __popcll(amb & ((1ull << lane) - 1ull)) + ((wl == 1) ? wc0s[g] : 0);
    __syncthreads();  // B3: wtot + iv visible
    int add = 0;
    for (int ww = 0; ww < wl; ++ww) add += wtot[g][ww];
    sIncl[g][u] = v + add;

    // ---- spin: thread t polls molecule t's word (one address each) ----
    {
        unsigned int val = __hip_atomic_load(&pub[t], __ATOMIC_RELAXED,
                                             __HIP_MEMORY_SCOPE_AGENT);
        while (!(val & 0x80000000u)) {
            __builtin_amdgcn_s_sleep(2);
            val = __hip_atomic_load(&pub[t], __ATOMIC_RELAXED,
                                    __HIP_MEMORY_SCOPE_AGENT);
        }
        pubR[t] = (int)(val & 0xFFu);
        pubP[t] = (int)((val >> 8) & 0x1FFFu);
    }
    __syncthreads();  // B4: sIncl + pubR/pubP visible

    // ---- per-subgroup redundant prefix over the LDS count table ----
    int4 ca = ((const int4*)pubR)[u];  // entries 4u..4u+3
    int4 cp = ((const int4*)pubP)[u];
    int i0 = 4 * u;
    int aLT = ((i0 + 0) < m ? ca.x : 0) + ((i0 + 1) < m ? ca.y : 0) +
              ((i0 + 2) < m ? ca.z : 0) + ((i0 + 3) < m ? ca.w : 0);
    int aALL = ca.x + ca.y + ca.z + ca.w;
    int pLT = ((i0 + 0) < m ? cp.x : 0) + ((i0 + 1) < m ? cp.y : 0) +
              ((i0 + 2) < m ? cp.z : 0) + ((i0 + 3) < m ? cp.w : 0);
    int pALL = cp.x + cp.y + cp.z + cp.w;
    for (int d = 32; d > 0; d >>= 1) {
        aLT += __shfl_down(aLT, d);
        aALL += __shfl_down(aALL, d);
        pLT += __shfl_down(pLT, d);
        pALL += __shfl_down(pALL, d);
    }
    if (lane == 0) { redALT[g][wl] = aLT; redAALL[g][wl] = aALL;
                     redPLT[g][wl] = pLT; redPALL[g][wl] = pALL; }
    __syncthreads();  // B5: red* visible

    int mol_base = redALT[g][0] + redALT[g][1] + redALT[g][2] + redALT[g][3];
    int n_real   = redAALL[g][0] + redAALL[g][1] + redAALL[g][2] + redAALL[g][3];
    int qbase    = redPLT[g][0] + redPLT[g][1] + redPLT[g][2] + redPLT[g][3];
    int npairs   = redPALL[g][0] + redPALL[g][1] + redPALL[g][2] + redPALL[g][3];

    // ---- atom outputs ----
    if (u < MOLSIZE && s_at > 0) {
        int gi = mol_base + iv[g][u];
        out[3074 + gi] = spf[g][u];
        out[3074 + n_real + gi] = (float)(u * (MOLSIZE + 1) + m * (MOLSIZE * MOLSIZE));
        out[3074 + 2 * n_real + gi] = (float)m;
    }
    int np_mol = sIncl[g][255];

    int offP = 3074 + 3 * n_real;
    float* pm0 = out + offP;
    float* pm1 = pm0 + npairs;
    float* pm2 = pm1 + npairs;
    float* pm3 = pm2 + npairs;
    float* pm4 = pm3 + npairs;
    float* pm5 = pm4 + npairs;
    float* px  = pm5 + npairs;
    float* pr  = px + 3 * npairs;
    float fm = (float)m;

    for (int q = u; q < np_mol; q += 256) {
        // binary search: c = first chunk with inclusive-scan > q
        int c = 0;
        if (sIncl[g][c + 127] <= q) c += 128;
        if (sIncl[g][c + 63] <= q) c += 64;
        if (sIncl[g][c + 31] <= q) c += 32;
        if (sIncl[g][c + 15] <= q) c += 16;
        if (sIncl[g][c + 7] <= q) c += 8;
        if (sIncl[g][c + 3] <= q) c += 4;
        if (sIncl[g][c + 1] <= q) c += 2;
        if (sIncl[g][c] <= q) c += 1;
        int r = q - (c ? sIncl[g][c - 1] : 0);
        unsigned long long mb = bal_s[g][c];
        // branchless select of r-th set bit
        unsigned int cur = (unsigned int)mb;
        int idx = 0;
        int cc = __popc(cur);
        if (r >= cc) { r -= cc; idx = 32; cur = (unsigned int)(mb >> 32); }
        cc = __popc(cur & 0xFFFFu); if (r >= cc) { r -= cc; idx += 16; cur >>= 16; }
        cc = __popc(cur & 0xFFu);   if (r >= cc) { r -= cc; idx += 8;  cur >>= 8; }
        cc = __popc(cur & 0xFu);    if (r >= cc) { r -= cc; idx += 4;  cur >>= 4; }
        cc = __popc(cur & 0x3u);    if (r >= cc) { r -= cc; idx += 2;  cur >>= 2; }
        cc = cur & 1u;              if (r >= cc) { idx += 1; }
        int a = c >> 1;
        int b = ((c & 1) << 6) | idx;
        float dx, dy, dz;
        float dist = pair_dist(cx[g][a], cy[g][a], cz[g][a],
                               cx[g][b], cy[g][b], cz[g][b], dx, dy, dz);
        int Q = qbase + q;
        pm0[Q] = (float)(m * (MOLSIZE * MOLSIZE) + a * MOLSIZE + b);
        pm1[Q] = fm;
        pm2[Q] = spf[g][a];
        pm3[Q] = spf[g][b];
        pm4[Q] = (float)(mol_base + iv[g][a]);
        pm5[Q] = (float)(mol_base + iv[g][b]);
        px[3 * Q + 0] = __fdiv_rn(dx, dist);
        px[3 * Q + 1] = __fdiv_rn(dy, dist);
        px[3 * Q + 2] = __fdiv_rn(dz, dist);
        pr[Q] = __fmul_rn(dist, 1.8897261258369282f);
    }
}

extern "C" void kernel_launch(void* const* d_in, const int* in_sizes, int n_in,
                              void* d_out, int out_size, void* d_ws, size_t ws_size,
                              hipStream_t stream) {
    const int* species = (const int*)d_in[0];
    const float* coords = (const float*)d_in[1];
    const float* tore = (const float*)d_in[2];
    float* out = (float*)d_out;
    unsigned int* pub = (unsigned int*)d_ws;

    // ws is re-poisoned each iteration -> publish flags MUST be zeroed first.
    hipMemsetAsync(pub, 0, NMOL * sizeof(unsigned int), stream);
    k_fused<<<NBLK, 1024, 0, stream>>>(species, coords, tore, out, pub);
}

// Round 3
// 78.118 us; speedup vs baseline: 1.0793x; 1.0163x over previous
//
#include <hip/hip_runtime.h>

#define NMOL 1024
#define MOLSIZE 128
#define MPB 4              // molecules per block (4 independent 256-thread subgroups)
#define NBLK (NMOL / MPB)  // 256 workgroups = 1 per CU

// Output layout (all float32, reference return order, flat):
// [0] nmol, [1] molsize, [2..2+1024) nHeavy, [1026..2050) nHydro, [2050..3074) nocc,
// [3074 +0/1/2*n_real) Z, maskd, atom_molid,
// P=3074+3*n_real: mask, pair_molid, ni, nj, idxi, idxj (np each), xij (3*np), rij (np)
//
// R8 structure (post-mortem of R7): R0 (2-kernel) == R7 (fused spin) at ~79.3us
// -> region is dominated by costs insensitive to structure. Trim everything
// still controllable:
//  1. NO memset node: dual-word publish {pub[m]=V, chk[m]=~V}; subscriber
//     accepts iff (v1&FLAG)&&(v2==~v1). Constant poison P can never validate
//     (P==~P impossible); every accept-path yields the true V. Single node.
//  2. Global 1024-wide prefix computed ONCE (subgroup 0), others fix up with
//     <=3 LDS reads.
//  3. Pair decode (binary search + bit select + dist math) is block-local ->
//     first 2 iterations computed into registers BEFORE the spin; only
//     +qbase/+mol_base and stores after.

// Exact-reference arithmetic: f32 sub, (x^2+y^2)+z^2 without fma, sqrt.
__device__ __forceinline__ float pair_dist(float ax, float ay, float az,
                                           float bx, float by, float bz,
                                           float& dx, float& dy, float& dz) {
    dx = __fsub_rn(bx, ax);
    dy = __fsub_rn(by, ay);
    dz = __fsub_rn(bz, az);
    float d2 = __fadd_rn(__fadd_rn(__fmul_rn(dx, dx), __fmul_rn(dy, dy)), __fmul_rn(dz, dz));
    return __fsqrt_rn(d2);
}

// Decode pair #q of this molecule from block-local LDS state. No barriers.
__device__ __forceinline__ void decode_pair(const int* __restrict__ sI,
                                            const unsigned long long* __restrict__ balp,
                                            const float* __restrict__ cxp,
                                            const float* __restrict__ cyp,
                                            const float* __restrict__ czp,
                                            const float* __restrict__ spfp,
                                            const int* __restrict__ ivp,
                                            int q, int m,
                                            float& maskf, float& sa, float& sb,
                                            float& x, float& y, float& z, float& r,
                                            int& iva, int& ivb) {
    // binary search: c = first chunk with inclusive-scan > q
    int c = 0;
    if (sI[c + 127] <= q) c += 128;
    if (sI[c + 63] <= q) c += 64;
    if (sI[c + 31] <= q) c += 32;
    if (sI[c + 15] <= q) c += 16;
    if (sI[c + 7] <= q) c += 8;
    if (sI[c + 3] <= q) c += 4;
    if (sI[c + 1] <= q) c += 2;
    if (sI[c] <= q) c += 1;
    int rr = q - (c ? sI[c - 1] : 0);
    unsigned long long mb = balp[c];
    // branchless select of rr-th set bit
    unsigned int cur = (unsigned int)mb;
    int idx = 0;
    int cc = __popc(cur);
    if (rr >= cc) { rr -= cc; idx = 32; cur = (unsigned int)(mb >> 32); }
    cc = __popc(cur & 0xFFFFu); if (rr >= cc) { rr -= cc; idx += 16; cur >>= 16; }
    cc = __popc(cur & 0xFFu);   if (rr >= cc) { rr -= cc; idx += 8;  cur >>= 8; }
    cc = __popc(cur & 0xFu);    if (rr >= cc) { rr -= cc; idx += 4;  cur >>= 4; }
    cc = __popc(cur & 0x3u);    if (rr >= cc) { rr -= cc; idx += 2;  cur >>= 2; }
    cc = cur & 1u;              if (rr >= cc) { idx += 1; }
    int a = c >> 1;
    int b = ((c & 1) << 6) | idx;
    float dx, dy, dz;
    float dist = pair_dist(cxp[a], cyp[a], czp[a], cxp[b], cyp[b], czp[b], dx, dy, dz);
    maskf = (float)(m * (MOLSIZE * MOLSIZE) + a * MOLSIZE + b);
    sa = spfp[a];
    sb = spfp[b];
    iva = ivp[a];
    ivb = ivp[b];
    x = __fdiv_rn(dx, dist);
    y = __fdiv_rn(dy, dist);
    z = __fdiv_rn(dz, dist);
    r = __fmul_rn(dist, 1.8897261258369282f);
}

__global__ __launch_bounds__(1024) void k_fused(const int* __restrict__ species,
                                                const float* __restrict__ coord,
                                                const float* __restrict__ tore,
                                                float* __restrict__ out,
                                                unsigned int* __restrict__ pub,
                                                unsigned int* __restrict__ chk) {
    __shared__ float cx[MPB][MOLSIZE], cy[MPB][MOLSIZE], cz[MPB][MOLSIZE], spf[MPB][MOLSIZE];
    __shared__ int iv[MPB][MOLSIZE];  // LOCAL nonblank rank (mol_base added at use)
    __shared__ unsigned long long bal_s[MPB][256];
    __shared__ int sIncl[MPB][256];
    __shared__ int sH[MPB][2], sY[MPB][2], sN[MPB][2];
    __shared__ float sT[MPB][2];
    __shared__ int wpair[MPB][4], wtot[MPB][4];
    __shared__ int wc0s[MPB];
    __shared__ __align__(16) int pubR[NMOL];
    __shared__ __align__(16) int pubP[NMOL];
    __shared__ int g0red[4][4];  // subgroup-0 per-wave partials: aLT0, aALL, pLT0, pALL

    int t = threadIdx.x;
    int g = t >> 8;        // subgroup = molecule slot 0..3
    int u = t & 255;       // thread index within subgroup
    int m = blockIdx.x * MPB + g;
    int lane = t & 63;     // lane within wave
    int wl = (t >> 6) & 3; // wave index within subgroup (0..3)

    // ---- phase A: load + mol stats (u<128 => 2 waves per subgroup; wave-uniform) ----
    int s_at = 0;
    unsigned long long amb = 0ull;
    if (u < MOLSIZE) {
        int f = m * MOLSIZE + u;
        s_at = species[f];
        bool nb = (s_at > 0);
        float x = coord[3 * f + 0], y = coord[3 * f + 1], z = coord[3 * f + 2];
        float sent = 1.0e30f * (float)(u + 1);  // blanks -> dist = inf, never selected
        cx[g][u] = nb ? x : sent;
        cy[g][u] = nb ? y : sent;
        cz[g][u] = nb ? z : sent;
        spf[g][u] = (float)s_at;
        amb = __ballot(nb);
        if (u == 0) wc0s[g] = __popcll(amb);
        int h = (s_at > 1) ? 1 : 0, yy = (s_at == 1) ? 1 : 0, nn = nb ? 1 : 0;
        float tv = tore[s_at];  // integer-valued: reduction order exact
        for (int d = 32; d > 0; d >>= 1) {
            h += __shfl_down(h, d);
            yy += __shfl_down(yy, d);
            nn += __shfl_down(nn, d);
            tv += __shfl_down(tv, d);
        }
        if (lane == 0) { sH[g][wl] = h; sY[g][wl] = yy; sN[g][wl] = nn; sT[g][wl] = tv; }
    }
    __syncthreads();  // B1: cx/cy/cz/spf + per-wave stats ready
    if (u == 0) {
        out[2 + m] = (float)(sH[g][0] + sH[g][1]);
        out[2 + NMOL + m] = (float)(sY[g][0] + sY[g][1]);
        out[2 + 2 * NMOL + m] = (float)((int)((sT[g][0] + sT[g][1]) * 0.5f));
        if (m == 0) { out[0] = (float)NMOL; out[1] = (float)MOLSIZE; }
    }

    // ---- phase B: pair ballot sweep (chunk c = 2*a + (b>=64), bit = b&63) ----
    float bxl = cx[g][lane], byl = cy[g][lane], bzl = cz[g][lane];
    float bxh = cx[g][64 + lane], byh = cy[g][64 + lane], bzh = cz[g][64 + lane];
    int wcount = 0;
    for (int j = 0; j < 32; ++j) {
        int a = wl + 4 * j;
        float ax = cx[g][a], ay = cy[g][a], az = cz[g][a];  // broadcast reads
        unsigned long long mb0 = 0ull, mb1 = 0ull;
        if (a < 63) {  // lo half: b = lane, need b > a
            float dx, dy, dz;
            float dist = pair_dist(ax, ay, az, bxl, byl, bzl, dx, dy, dz);
            mb0 = __ballot((lane > a) && (dist < 5.0f));
        }
        if (a < 127) {  // hi half: b = 64+lane, need b > a (matters for a >= 64!)
            float dx, dy, dz;
            float dist = pair_dist(ax, ay, az, bxh, byh, bzh, dx, dy, dz);
            mb1 = __ballot(((64 + lane) > a) && (dist < 5.0f));
        }
        if (lane == 0) { bal_s[g][2 * a] = mb0; bal_s[g][2 * a + 1] = mb1; }
        wcount += __popcll(mb0) + __popcll(mb1);
    }
    if (lane == 0) wpair[g][wl] = wcount;
    __syncthreads();  // B2: bal_s + wpair complete

    // ---- dual-word publish (poison-proof: accept iff flag && chk==~pub) ----
    if (u == 0) {
        unsigned int nreal = (unsigned int)(sN[g][0] + sN[g][1]);
        unsigned int ptot =
            (unsigned int)(wpair[g][0] + wpair[g][1] + wpair[g][2] + wpair[g][3]);
        unsigned int word = 0x80000000u | (ptot << 8) | nreal;
        __hip_atomic_store(&pub[m], word, __ATOMIC_RELAXED, __HIP_MEMORY_SCOPE_AGENT);
        __hip_atomic_store(&chk[m], ~word, __ATOMIC_RELAXED, __HIP_MEMORY_SCOPE_AGENT);
    }

    // ---- local scan work (overlaps other blocks publishing) ----
    unsigned long long bal = bal_s[g][u];
    int v = __popcll(bal);
    for (int d = 1; d < 64; d <<= 1) {
        int uu = __shfl_up(v, d);
        if (lane >= d) v += uu;
    }
    if (lane == 63) wtot[g][wl] = v;
    if (u < MOLSIZE && s_at > 0)
        iv[g][u] = __popcll(amb & ((1ull << lane) - 1ull)) + ((wl == 1) ? wc0s[g] : 0);
    __syncthreads();  // B3: wtot + iv visible
    int add = 0;
    for (int ww = 0; ww < wl; ++ww) add += wtot[g][ww];
    sIncl[g][u] = v + add;
    __syncthreads();  // B3b: sIncl visible

    // ---- decode-under-spin: first 2 pair iterations into registers ----
    int np_mol = sIncl[g][255];
    const int* sI = sIncl[g];
    const unsigned long long* balp = bal_s[g];
    const float* cxp = cx[g];
    const float* cyp = cy[g];
    const float* czp = cz[g];
    const float* spfp = spf[g];
    const int* ivp = iv[g];

    float mk0, sa0, sb0, x0, y0, z0, r0;
    int ia0 = 0, ib0 = 0;
    bool h0 = (u < np_mol);
    if (h0) decode_pair(sI, balp, cxp, cyp, czp, spfp, ivp, u, m,
                        mk0, sa0, sb0, x0, y0, z0, r0, ia0, ib0);
    float mk1, sa1, sb1, x1, y1, z1, r1;
    int ia1 = 0, ib1 = 0;
    bool h1 = (u + 256 < np_mol);
    if (h1) decode_pair(sI, balp, cxp, cyp, czp, spfp, ivp, u + 256, m,
                        mk1, sa1, sb1, x1, y1, z1, r1, ia1, ib1);

    // ---- spin: thread t polls molecule t's word pair ----
    {
        unsigned int v1 = __hip_atomic_load(&pub[t], __ATOMIC_RELAXED,
                                            __HIP_MEMORY_SCOPE_AGENT);
        unsigned int v2 = __hip_atomic_load(&chk[t], __ATOMIC_RELAXED,
                                            __HIP_MEMORY_SCOPE_AGENT);
        while (!((v1 & 0x80000000u) && (v2 == ~v1))) {
            __builtin_amdgcn_s_sleep(2);
            v1 = __hip_atomic_load(&pub[t], __ATOMIC_RELAXED, __HIP_MEMORY_SCOPE_AGENT);
            v2 = __hip_atomic_load(&chk[t], __ATOMIC_RELAXED, __HIP_MEMORY_SCOPE_AGENT);
        }
        pubR[t] = (int)(v1 & 0xFFu);
        pubP[t] = (int)((v1 >> 8) & 0x1FFFu);
    }
    __syncthreads();  // B4: pubR/pubP staged

    // ---- global prefix for m0 = first molecule of block: subgroup 0 only ----
    int m0 = blockIdx.x * MPB;
    if (t < 256) {
        int4 ca = ((const int4*)pubR)[t];  // entries 4t..4t+3
        int4 cp = ((const int4*)pubP)[t];
        int i0 = 4 * t;
        int aLT = ((i0 + 0) < m0 ? ca.x : 0) + ((i0 + 1) < m0 ? ca.y : 0) +
                  ((i0 + 2) < m0 ? ca.z : 0) + ((i0 + 3) < m0 ? ca.w : 0);
        int aALL = ca.x + ca.y + ca.z + ca.w;
        int pLT = ((i0 + 0) < m0 ? cp.x : 0) + ((i0 + 1) < m0 ? cp.y : 0) +
                  ((i0 + 2) < m0 ? cp.z : 0) + ((i0 + 3) < m0 ? cp.w : 0);
        int pALL = cp.x + cp.y + cp.z + cp.w;
        for (int d = 32; d > 0; d >>= 1) {
            aLT += __shfl_down(aLT, d);
            aALL += __shfl_down(aALL, d);
            pLT += __shfl_down(pLT, d);
            pALL += __shfl_down(pALL, d);
        }
        if (lane == 0) {
            g0red[t >> 6][0] = aLT;
            g0red[t >> 6][1] = aALL;
            g0red[t >> 6][2] = pLT;
            g0red[t >> 6][3] = pALL;
        }
    }
    __syncthreads();  // B5: g0red visible

    int mol_base = g0red[0][0] + g0red[1][0] + g0red[2][0] + g0red[3][0];
    int n_real   = g0red[0][1] + g0red[1][1] + g0red[2][1] + g0red[3][1];
    int qbase    = g0red[0][2] + g0red[1][2] + g0red[2][2] + g0red[3][2];
    int npairs   = g0red[0][3] + g0red[1][3] + g0red[2][3] + g0red[3][3];
    for (int k = 0; k < g; ++k) {  // wave-uniform fixup (<=3 broadcast LDS reads)
        mol_base += pubR[m0 + k];
        qbase += pubP[m0 + k];
    }

    // ---- atom outputs ----
    if (u < MOLSIZE && s_at > 0) {
        int gi = mol_base + iv[g][u];
        out[3074 + gi] = spf[g][u];
        out[3074 + n_real + gi] = (float)(u * (MOLSIZE + 1) + m * (MOLSIZE * MOLSIZE));
        out[3074 + 2 * n_real + gi] = (float)m;
    }

    int offP = 3074 + 3 * n_real;
    float* pm0 = out + offP;
    float* pm1 = pm0 + npairs;
    float* pm2 = pm1 + npairs;
    float* pm3 = pm2 + npairs;
    float* pm4 = pm3 + npairs;
    float* pm5 = pm4 + npairs;
    float* px  = pm5 + npairs;
    float* pr  = px + 3 * npairs;
    float fm = (float)m;

    if (h0) {
        int Q = qbase + u;
        pm0[Q] = mk0; pm1[Q] = fm; pm2[Q] = sa0; pm3[Q] = sb0;
        pm4[Q] = (float)(mol_base + ia0);
        pm5[Q] = (float)(mol_base + ib0);
        px[3 * Q + 0] = x0; px[3 * Q + 1] = y0; px[3 * Q + 2] = z0;
        pr[Q] = r0;
    }
    if (h1) {
        int Q = qbase + u + 256;
        pm0[Q] = mk1; pm1[Q] = fm; pm2[Q] = sa1; pm3[Q] = sb1;
        pm4[Q] = (float)(mol_base + ia1);
        pm5[Q] = (float)(mol_base + ib1);
        px[3 * Q + 0] = x1; px[3 * Q + 1] = y1; px[3 * Q + 2] = z1;
        pr[Q] = r1;
    }
    for (int q = u + 512; q < np_mol; q += 256) {  // rare tail (np_mol > 512)
        float mk, sa, sb, x, y, z, r;
        int ia, ib;
        decode_pair(sI, balp, cxp, cyp, czp, spfp, ivp, q, m,
                    mk, sa, sb, x, y, z, r, ia, ib);
        int Q = qbase + q;
        pm0[Q] = mk; pm1[Q] = fm; pm2[Q] = sa; pm3[Q] = sb;
        pm4[Q] = (float)(mol_base + ia);
        pm5[Q] = (float)(mol_base + ib);
        px[3 * Q + 0] = x; px[3 * Q + 1] = y; px[3 * Q + 2] = z;
        pr[Q] = r;
    }
}

extern "C" void kernel_launch(void* const* d_in, const int* in_sizes, int n_in,
                              void* d_out, int out_size, void* d_ws, size_t ws_size,
                              hipStream_t stream) {
    const int* species = (const int*)d_in[0];
    const float* coords = (const float*)d_in[1];
    const float* tore = (const float*)d_in[2];
    float* out = (float*)d_out;
    unsigned int* pub = (unsigned int*)d_ws;
    unsigned int* chk = pub + NMOL;

    // Single node: dual-word publish protocol is poison-proof, no memset needed.
    k_fused<<<NBLK, 1024, 0, stream>>>(species, coords, tore, out, pub, chk);
}